// Round 1
// 1294.417 us; speedup vs baseline: 1.0388x; 1.0388x over previous
//
#include <hip/hip_runtime.h>

// ---------------------------------------------------------------------------
// MoE LM forward, MI355X round 3.
// Dual-dtype (runtime-sniffed bf16 vs f32 inputs/outputs), f32 accumulation.
// Pipeline: k_sniff -> k_transpose -> k_embed_pre -> k_scan -> k_ffn
//           -> k_gates -> k_ln -> k_head.
// R3: k_scan rewritten -- __launch_bounds__(64,1) so the Um column stays in
//     VGPRs (prev build had VGPR_Count=44 => Um reloaded from L2 every step),
//     v_pk_fma-friendly f32x2 dot, no __syncthreads (single wave, explicit
//     lgkmcnt(0) after the LDS write).  k_embed_pre: 4 threads/token.
// ---------------------------------------------------------------------------

#define VV 16000
#define BB 8
#define TT 1024
#define DD 64
#define FF 256
#define EE 8
#define BT 8192   // B*T

typedef unsigned short u16;
typedef unsigned int   u32;
typedef __attribute__((ext_vector_type(8))) short short8;   // 8 x bf16 (4 VGPR)
typedef __attribute__((ext_vector_type(4))) float f32x4;    // MFMA C/D
typedef __attribute__((ext_vector_type(2))) float f32x2;    // v_pk_fma_f32

__device__ __forceinline__ float bf2f(u16 u) {
    union { u32 i; float f; } v; v.i = ((u32)u) << 16; return v.f;
}
__device__ __forceinline__ u16 f2bf(float f) {  // round-to-nearest-even
    union { float f; u32 i; } v; v.f = f;
    u32 lsb = (v.i >> 16) & 1u;
    return (u16)((v.i + 0x7fffu + lsb) >> 16);
}
__device__ __forceinline__ short8 ld8(const u16* p) { return *(const short8*)p; }
// dual-dtype scalar load: input array is bf16 (isbf=1) or f32 (isbf=0)
__device__ __forceinline__ float ldf(const void* p, int i, int isbf) {
    return isbf ? bf2f(((const u16*)p)[i]) : ((const float*)p)[i];
}

// ---------------------------------------------------------------------------
// K-1: dtype sniffer. In bf16-packed data the LOW 16 bits of each u32 word
// are a bf16 value with exponent in a narrow plausible band; in f32 data
// they are uniform mantissa bits. 256 samples, majority vote.
// ---------------------------------------------------------------------------
__global__ __launch_bounds__(256) void k_sniff(const u32* __restrict__ tblw,
                                               int* __restrict__ flag) {
    __shared__ int c;
    int tid = threadIdx.x;
    if (tid == 0) c = 0;
    __syncthreads();
    u32 u = tblw[tid];
    u32 lo = u & 0xFFFFu;
    u32 e = (lo >> 7) & 0xFFu;
    int hit = ((e >= 0x60u && e <= 0x7Eu) || lo == 0u) ? 1 : 0;
    atomicAdd(&c, hit);
    __syncthreads();
    if (tid == 0) *flag = (c >= 192) ? 1 : 0;
}

// ---------------------------------------------------------------------------
// K0: convert+transpose weights to canonical bf16, B^T layout for MFMA.
//   headWT[v][k] = head_W[k][v]; W1T[e][f][d] = W1[e][d][f];
//   W2T[e][d][f] = W2[e][f][d]
// ---------------------------------------------------------------------------
__global__ __launch_bounds__(256) void k_transpose(const void* __restrict__ headW,
                                                   const void* __restrict__ W1,
                                                   const void* __restrict__ W2,
                                                   const int* __restrict__ flag,
                                                   u16* __restrict__ headWT,
                                                   u16* __restrict__ W1T,
                                                   u16* __restrict__ W2T) {
    int isbf = *flag;
    int idx = blockIdx.x * 256 + threadIdx.x;
    if (idx < DD * VV) {                       // 1,024,000
        int k = idx / VV, n = idx - k * VV;
        headWT[n * DD + k] = f2bf(ldf(headW, idx, isbf));
    } else if (idx < DD * VV + EE * DD * FF) { // + 131,072
        int j = idx - DD * VV;
        int e = j >> 14, r = j & 16383, d = r >> 8, f = r & 255;
        W1T[e * 16384 + f * DD + d] = f2bf(ldf(W1, j, isbf));
    } else if (idx < DD * VV + 2 * EE * DD * FF) {
        int j = idx - DD * VV - EE * DD * FF;
        int e = j >> 14, r = j & 16383, f = r >> 6, d = r & 63;
        W2T[e * 16384 + d * FF + f] = f2bf(ldf(W2, j, isbf));
    }
}

// ---------------------------------------------------------------------------
// K1: gather embeddings (-> canonical bf16 emb) + pre[t][b][:] = emb@Wm + bm.
//     R3: 4 threads per token (q = quarter of the 64 output columns),
//     float4 LDS reads; summation order per output unchanged.
// ---------------------------------------------------------------------------
__global__ __launch_bounds__(256) void k_embed_pre(const int* __restrict__ x,
                                                   const void* __restrict__ tbl,
                                                   const void* __restrict__ Wm,
                                                   const void* __restrict__ bm,
                                                   const int* __restrict__ flag,
                                                   u16* __restrict__ emb,
                                                   float* __restrict__ pre) {
    __shared__ float sWm[DD * DD];
    __shared__ float sbm[DD];
    int isbf = *flag;
    int tid = threadIdx.x;
    for (int i = tid; i < DD * DD; i += 256) sWm[i] = ldf(Wm, i, isbf);
    if (tid < DD) sbm[tid] = ldf(bm, tid, isbf);
    __syncthreads();

    int gi = blockIdx.x * 256 + tid;           // grid = 128
    int tok = gi >> 2, q = gi & 3;             // 4 threads per token
    int id = x[tok];
    float e[DD];
    if (isbf) {
        const uint4* src = (const uint4*)((const u16*)tbl + id * DD);
        uint4* dst = (uint4*)(emb + tok * DD);
#pragma unroll
        for (int i = 0; i < 8; i++) {
            uint4 v = src[i];
            if ((i >> 1) == q) dst[i] = v;     // each q writes 2 of 8 uint4
            const u16* pu = (const u16*)&v;
#pragma unroll
            for (int j = 0; j < 8; j++) e[i * 8 + j] = bf2f(pu[j]);
        }
    } else {
        const float4* src = (const float4*)((const float*)tbl + id * DD);
        u16* dst = emb + tok * DD;
#pragma unroll
        for (int i = 0; i < 16; i++) {
            float4 v = src[i];
            e[i * 4 + 0] = v.x; e[i * 4 + 1] = v.y;
            e[i * 4 + 2] = v.z; e[i * 4 + 3] = v.w;
            if ((i >> 2) == q) {               // each q writes 4 of 16 pairs
                u32 p0 = (u32)f2bf(v.x) | ((u32)f2bf(v.y) << 16);
                u32 p1 = (u32)f2bf(v.z) | ((u32)f2bf(v.w) << 16);
                ((u32*)dst)[i * 2] = p0;
                ((u32*)dst)[i * 2 + 1] = p1;
            }
        }
    }
    int b = tok >> 10, t = tok & 1023;
    float* prow = pre + (t * BB + b) * DD + q * 16;
#pragma unroll
    for (int j4 = 0; j4 < 4; j4++) {
        int j0 = q * 16 + j4 * 4;
        float a0 = sbm[j0 + 0], a1 = sbm[j0 + 1];
        float a2 = sbm[j0 + 2], a3 = sbm[j0 + 3];
#pragma unroll
        for (int k = 0; k < DD; k++) {
            float ek = e[k];
            float4 wv = *(const float4*)&sWm[k * DD + j0];
            a0 += ek * wv.x; a1 += ek * wv.y;
            a2 += ek * wv.z; a3 += ek * wv.w;
        }
        ((float4*)prow)[j4] = make_float4(a0, a1, a2, a3);
    }
}

// ---------------------------------------------------------------------------
// K2: serial scan. 8 blocks (one per batch row), 1 wave each.
//     lane j owns column j; Um column j in 64 VGPRs (f32x2 pairs for
//     v_pk_fma_f32); mem vector broadcast through LDS.
//     mem_t = tanh(pre_t + mem_{t-1} @ Um), stored f32 [t][b][d].
//     Single wave => no s_barrier needed; DS ops of one wave complete in
//     order, explicit lgkmcnt(0) after the sm write is the only fence
//     (avoids __syncthreads' vmcnt(0) drain of the mem store / pre prefetch).
// ---------------------------------------------------------------------------
__global__ __launch_bounds__(64, 1) void k_scan(const float* __restrict__ pre,
                                                const void* __restrict__ Um,
                                                const int* __restrict__ flag,
                                                float* __restrict__ mem) {
    int isbf = *flag;
    int b = blockIdx.x, j = threadIdx.x;
    __shared__ float sm[DD];

    // Um column j, loaded ONCE into 32 f32x2 (64 VGPRs).
    f32x2 um2[32];
    if (isbf) {
        const u16* up = (const u16*)Um + j;
#pragma unroll
        for (int kk = 0; kk < 32; kk++) {
            f32x2 v; v.x = bf2f(up[(2 * kk) * DD]); v.y = bf2f(up[(2 * kk + 1) * DD]);
            um2[kk] = v;
        }
    } else {
        const float* up = (const float*)Um + j;
#pragma unroll
        for (int kk = 0; kk < 32; kk++) {
            f32x2 v; v.x = up[(2 * kk) * DD]; v.y = up[(2 * kk + 1) * DD];
            um2[kk] = v;
        }
    }
    sm[j] = 0.f;
    asm volatile("s_waitcnt lgkmcnt(0)" ::: "memory");

    float pcur = pre[b * DD + j];   // t = 0
    for (int t = 0; t < TT; t++) {
        int tn = (t + 1 < TT) ? t + 1 : t;
        float pnext = pre[(tn * BB + b) * DD + j];   // prefetch (vmcnt only)
        // dot(mem, Um[:,j]); accumulator pairing identical to prev build:
        // Acc0 = (a0,a1) over k%4 in {0,1}, Acc1 = (a2,a3) over k%4 in {2,3}.
        f32x2 Acc0 = {0.f, 0.f}, Acc1 = {0.f, 0.f};
        const f32x4* m4 = (const f32x4*)sm;
#pragma unroll
        for (int k4 = 0; k4 < 16; k4++) {
            f32x4 m = m4[k4];
            f32x2 mlo = __builtin_shufflevector(m, m, 0, 1);
            f32x2 mhi = __builtin_shufflevector(m, m, 2, 3);
            Acc0 += mlo * um2[2 * k4];
            Acc1 += mhi * um2[2 * k4 + 1];
        }
        float s = ((Acc0.x + Acc0.y) + (Acc1.x + Acc1.y)) + pcur;
        // tanh(s) = 1 - 2/(e^{2s}+1); exp->inf / ->0 both give correct +/-1
        float ex = __expf(2.f * s);
        float mn = 1.f - 2.f * __builtin_amdgcn_rcpf(ex + 1.f);
        sm[j] = mn;
        asm volatile("s_waitcnt lgkmcnt(0)" ::: "memory");
        mem[(t * BB + b) * DD + j] = mn;
        pcur = pnext;
    }
}

// ---------------------------------------------------------------------------
// K3: expert FFN. block = (expert e, 64 tokens); wave w = 16 tokens.
//     GEMM1: h = gelu(emb @ W1_e + b1_e); LDS round-trip (C->A layout);
//     GEMM2: eo = h @ W2_e + b2_e -> bf16 eo[tok][e][d].
// ---------------------------------------------------------------------------
__global__ __launch_bounds__(256) void k_ffn(const u16* __restrict__ emb,
                                             const u16* __restrict__ W1T,
                                             const void* __restrict__ b1g,
                                             const u16* __restrict__ W2T,
                                             const void* __restrict__ b2g,
                                             const int* __restrict__ flag,
                                             u16* __restrict__ eo) {
    __shared__ u16 hh[4][16 * 264];          // 264 = 256 + 8 pad
    int isbf = *flag;
    int e = blockIdx.x, mb = blockIdx.y;
    int w = threadIdx.x >> 6, l = threadIdx.x & 63;
    int lr = l & 15, lq = l >> 4;
    int m0 = mb * 64 + w * 16;

    short8 a0 = ld8(emb + (m0 + lr) * DD + lq * 8);
    short8 a1 = ld8(emb + (m0 + lr) * DD + 32 + lq * 8);
    const u16* w1 = W1T + e * 16384;

    f32x4 acc[16];
#pragma unroll
    for (int nt = 0; nt < 16; nt++) {
        int n = nt * 16 + lr;
        short8 bf0 = ld8(w1 + n * DD + lq * 8);
        short8 bf1 = ld8(w1 + n * DD + 32 + lq * 8);
        f32x4 c = {0.f, 0.f, 0.f, 0.f};
        c = __builtin_amdgcn_mfma_f32_16x16x32_bf16(a0, bf0, c, 0, 0, 0);
        c = __builtin_amdgcn_mfma_f32_16x16x32_bf16(a1, bf1, c, 0, 0, 0);
        acc[nt] = c;
    }
    u16* hw = hh[w];
#pragma unroll
    for (int nt = 0; nt < 16; nt++) {
        int n = nt * 16 + lr;
        float bb = ldf(b1g, e * FF + n, isbf);
#pragma unroll
        for (int r = 0; r < 4; r++) {
            float xv = acc[nt][r] + bb;
            float g = 0.5f * xv * (1.f + erff(xv * 0.70710678118654752f));
            hw[(lq * 4 + r) * 264 + n] = f2bf(g);
        }
    }
    __syncthreads();

    f32x4 acc2[4];
#pragma unroll
    for (int dt = 0; dt < 4; dt++) acc2[dt] = (f32x4){0.f, 0.f, 0.f, 0.f};
    const u16* w2 = W2T + e * 16384;
#pragma unroll
    for (int kb = 0; kb < 8; kb++) {
        short8 af = ld8(hw + lr * 264 + kb * 32 + lq * 8);
#pragma unroll
        for (int dt = 0; dt < 4; dt++) {
            short8 bf = ld8(w2 + (dt * 16 + lr) * FF + kb * 32 + lq * 8);
            acc2[dt] = __builtin_amdgcn_mfma_f32_16x16x32_bf16(af, bf, acc2[dt], 0, 0, 0);
        }
    }
#pragma unroll
    for (int dt = 0; dt < 4; dt++) {
        int d = dt * 16 + lr;
        float bb = ldf(b2g, e * DD + d, isbf);
#pragma unroll
        for (int r = 0; r < 4; r++) {
            int tok = m0 + lq * 4 + r;
            eo[(tok * EE + e) * DD + d] = f2bf(acc2[dt][r] + bb);
        }
    }
}

// ---------------------------------------------------------------------------
// K4: gates[tok][:] = softmax(mem[t][b][:] @ Wg + bg).  thread = token.
// ---------------------------------------------------------------------------
__global__ __launch_bounds__(256) void k_gates(const float* __restrict__ mem,
                                               const void* __restrict__ Wg,
                                               const void* __restrict__ bg,
                                               const int* __restrict__ flag,
                                               float* __restrict__ gates) {
    __shared__ float sWg[DD * EE];
    int isbf = *flag;
    int tid = threadIdx.x;
    for (int i = tid; i < DD * EE; i += 256) sWg[i] = ldf(Wg, i, isbf);
    __syncthreads();

    int tok = blockIdx.x * 256 + tid;
    int b = tok >> 10, t = tok & 1023;
    const float* mr = mem + (t * BB + b) * DD;
    float z[EE];
#pragma unroll
    for (int e = 0; e < EE; e++) z[e] = ldf(bg, e, isbf);
    const float4* wg4 = (const float4*)sWg;
    const float4* mr4 = (const float4*)mr;
    for (int k4 = 0; k4 < 16; k4++) {
        float4 mv = mr4[k4];
        float m[4] = {mv.x, mv.y, mv.z, mv.w};
#pragma unroll
        for (int kk = 0; kk < 4; kk++) {
            int k = k4 * 4 + kk;
            float4 wa = wg4[k * 2], wb = wg4[k * 2 + 1];
            z[0] += m[kk] * wa.x; z[1] += m[kk] * wa.y;
            z[2] += m[kk] * wa.z; z[3] += m[kk] * wa.w;
            z[4] += m[kk] * wb.x; z[5] += m[kk] * wb.y;
            z[6] += m[kk] * wb.z; z[7] += m[kk] * wb.w;
        }
    }
    float zm = z[0];
#pragma unroll
    for (int e = 1; e < EE; e++) zm = fmaxf(zm, z[e]);
    float sum = 0.f;
#pragma unroll
    for (int e = 0; e < EE; e++) { z[e] = __expf(z[e] - zm); sum += z[e]; }
    float rs = __builtin_amdgcn_rcpf(sum);
#pragma unroll
    for (int e = 0; e < EE; e++) gates[tok * EE + e] = z[e] * rs;
}

// ---------------------------------------------------------------------------
// K5: out = LayerNorm(emb + sum_e gates_e * eo_e) -> canonical bf16 outb.
// ---------------------------------------------------------------------------
__global__ __launch_bounds__(256) void k_ln(const u16* __restrict__ emb,
                                            const u16* __restrict__ eo,
                                            const float* __restrict__ gates,
                                            const void* __restrict__ ln_g,
                                            const void* __restrict__ ln_b,
                                            const int* __restrict__ flag,
                                            u16* __restrict__ outb) {
    int isbf = *flag;
    int w = threadIdx.x >> 6, l = threadIdx.x & 63;
    int tok = blockIdx.x * 4 + w;
    const float* g = gates + tok * EE;
    const u16* er = eo + tok * EE * DD;
    float moe = 0.f;
#pragma unroll
    for (int e = 0; e < EE; e++) moe += g[e] * bf2f(er[e * DD + l]);
    float y = bf2f(emb[tok * DD + l]) + moe;
    float s = y;
#pragma unroll
    for (int off = 32; off > 0; off >>= 1) s += __shfl_xor(s, off, 64);
    float mu = s * (1.f / 64.f);
    float d = y - mu;
    float s2 = d * d;
#pragma unroll
    for (int off = 32; off > 0; off >>= 1) s2 += __shfl_xor(s2, off, 64);
    float var = s2 * (1.f / 64.f);
    float r = rsqrtf(var + 1e-5f);
    float o = ldf(ln_g, l, isbf) * d * r + ldf(ln_b, l, isbf);
    outb[tok * DD + l] = f2bf(o);
}

// ---------------------------------------------------------------------------
// K6: head GEMM. logits = out @ head_W + head_b  [8192 x 16000].
//     Output dtype per flag (bf16 or f32).
// ---------------------------------------------------------------------------
__global__ __launch_bounds__(256) void k_head(const u16* __restrict__ outb,
                                              const u16* __restrict__ headWT,
                                              const void* __restrict__ head_b,
                                              const int* __restrict__ flag,
                                              void* __restrict__ logits) {
    int isbf = *flag;
    int nb = blockIdx.x, mb = blockIdx.y;
    int w = threadIdx.x >> 6, l = threadIdx.x & 63;
    int lr = l & 15, lq = l >> 4;
    int m0 = mb * 64 + w * 16;
    int n0 = nb * 256;
    int ntc = (nb == 62) ? 8 : 16;

    short8 a0 = ld8(outb + (m0 + lr) * DD + lq * 8);
    short8 a1 = ld8(outb + (m0 + lr) * DD + 32 + lq * 8);

    for (int nt = 0; nt < ntc; nt++) {
        int n = n0 + nt * 16 + lr;
        short8 bf0 = ld8(headWT + n * DD + lq * 8);
        short8 bf1 = ld8(headWT + n * DD + 32 + lq * 8);
        f32x4 c = {0.f, 0.f, 0.f, 0.f};
        c = __builtin_amdgcn_mfma_f32_16x16x32_bf16(a0, bf0, c, 0, 0, 0);
        c = __builtin_amdgcn_mfma_f32_16x16x32_bf16(a1, bf1, c, 0, 0, 0);
        float hb = ldf(head_b, n, isbf);
        if (isbf) {
#pragma unroll
            for (int r = 0; r < 4; r++)
                ((u16*)logits)[(m0 + lq * 4 + r) * VV + n] = f2bf(c[r] + hb);
        } else {
#pragma unroll
            for (int r = 0; r < 4; r++)
                ((float*)logits)[(m0 + lq * 4 + r) * VV + n] = c[r] + hb;
        }
    }
}

// ---------------------------------------------------------------------------
extern "C" void kernel_launch(void* const* d_in, const int* in_sizes, int n_in,
                              void* d_out, int out_size, void* d_ws, size_t ws_size,
                              hipStream_t stream) {
    const int*  x      = (const int*)d_in[0];
    const void* tbl    = d_in[1];
    const void* Wm     = d_in[2];
    const void* Um     = d_in[3];
    const void* bm     = d_in[4];
    const void* Wg     = d_in[5];
    const void* bg     = d_in[6];
    const void* W1     = d_in[7];
    const void* b1     = d_in[8];
    const void* W2     = d_in[9];
    const void* b2     = d_in[10];
    const void* ln_g   = d_in[11];
    const void* ln_b   = d_in[12];
    const void* headW  = d_in[13];
    const void* head_b = d_in[14];

    char* w = (char*)d_ws;
    int*   flag   = (int*)(w);                    // 256 B
    u16*   headWT = (u16*)(w + 0x0000100);        // 2,048,000 B
    u16*   W1T    = (u16*)(w + 0x0200000);        //   262,144 B
    u16*   W2T    = (u16*)(w + 0x0240000);        //   262,144 B
    u16*   emb    = (u16*)(w + 0x0280000);        // 1,048,576 B
    u16*   outb   = (u16*)(w + 0x0380000);        // 1,048,576 B
    float* pre    = (float*)(w + 0x0480000);      // 2,097,152 B
    float* mem    = (float*)(w + 0x0680000);      // 2,097,152 B
    float* gates  = (float*)(w + 0x0880000);      //   262,144 B
    u16*   eo     = (u16*)(w + 0x08C0000);        // 8,388,608 B  (end 17.6 MB)

    k_sniff<<<dim3(1), dim3(256), 0, stream>>>((const u32*)tbl, flag);
    k_transpose<<<dim3((DD * VV + 2 * EE * DD * FF + 255) / 256), dim3(256), 0, stream>>>(
        headW, W1, W2, flag, headWT, W1T, W2T);
    k_embed_pre<<<dim3(BT * 4 / 256), dim3(256), 0, stream>>>(x, tbl, Wm, bm, flag, emb, pre);
    k_scan<<<dim3(BB), dim3(64), 0, stream>>>(pre, Um, flag, mem);
    k_ffn<<<dim3(EE, BT / 64), dim3(256), 0, stream>>>(emb, W1T, b1, W2T, b2, flag, eo);
    k_gates<<<dim3(BT / 256), dim3(256), 0, stream>>>(mem, Wg, bg, flag, gates);
    k_ln<<<dim3(BT / 4), dim3(256), 0, stream>>>(emb, eo, gates, ln_g, ln_b, flag, outb);
    k_head<<<dim3(63, BT / 64), dim3(256), 0, stream>>>(outb, headWT, head_b, flag, d_out);
}

// Round 2
// 1024.878 us; speedup vs baseline: 1.3120x; 1.2630x over previous
//
#include <hip/hip_runtime.h>

// ---------------------------------------------------------------------------
// MoE LM forward, MI355X round 4.
// Dual-dtype (runtime-sniffed bf16 vs f32 inputs/outputs), f32 accumulation.
// Pipeline: k_sniff -> k_transpose -> k_embed_pre -> k_scan -> k_ffn
//           -> k_gates -> k_ln -> k_head.
// R4: k_scan Um column in 32 NAMED f32x2 vars (R2/R3 array forms both
//     compiled to VGPR_Count=44 => array demoted to scratch, re-loaded every
//     serial step; the asm "memory" clobber blocked hoist/remat).  No inline
//     asm, no __syncthreads: single-wave DS ops are in-order, compiler
//     inserts minimal lgkmcnt.
// ---------------------------------------------------------------------------

#define VV 16000
#define BB 8
#define TT 1024
#define DD 64
#define FF 256
#define EE 8
#define BT 8192   // B*T

typedef unsigned short u16;
typedef unsigned int   u32;
typedef __attribute__((ext_vector_type(8))) short short8;   // 8 x bf16 (4 VGPR)
typedef __attribute__((ext_vector_type(4))) float f32x4;    // MFMA C/D
typedef __attribute__((ext_vector_type(2))) float f32x2;    // v_pk_fma_f32

__device__ __forceinline__ float bf2f(u16 u) {
    union { u32 i; float f; } v; v.i = ((u32)u) << 16; return v.f;
}
__device__ __forceinline__ u16 f2bf(float f) {  // round-to-nearest-even
    union { float f; u32 i; } v; v.f = f;
    u32 lsb = (v.i >> 16) & 1u;
    return (u16)((v.i + 0x7fffu + lsb) >> 16);
}
__device__ __forceinline__ short8 ld8(const u16* p) { return *(const short8*)p; }
// dual-dtype scalar load: input array is bf16 (isbf=1) or f32 (isbf=0)
__device__ __forceinline__ float ldf(const void* p, int i, int isbf) {
    return isbf ? bf2f(((const u16*)p)[i]) : ((const float*)p)[i];
}

// ---------------------------------------------------------------------------
// K-1: dtype sniffer. In bf16-packed data the LOW 16 bits of each u32 word
// are a bf16 value with exponent in a narrow plausible band; in f32 data
// they are uniform mantissa bits. 256 samples, majority vote.
// ---------------------------------------------------------------------------
__global__ __launch_bounds__(256) void k_sniff(const u32* __restrict__ tblw,
                                               int* __restrict__ flag) {
    __shared__ int c;
    int tid = threadIdx.x;
    if (tid == 0) c = 0;
    __syncthreads();
    u32 u = tblw[tid];
    u32 lo = u & 0xFFFFu;
    u32 e = (lo >> 7) & 0xFFu;
    int hit = ((e >= 0x60u && e <= 0x7Eu) || lo == 0u) ? 1 : 0;
    atomicAdd(&c, hit);
    __syncthreads();
    if (tid == 0) *flag = (c >= 192) ? 1 : 0;
}

// ---------------------------------------------------------------------------
// K0: convert+transpose weights to canonical bf16, B^T layout for MFMA.
//   headWT[v][k] = head_W[k][v]; W1T[e][f][d] = W1[e][d][f];
//   W2T[e][d][f] = W2[e][f][d]
// ---------------------------------------------------------------------------
__global__ __launch_bounds__(256) void k_transpose(const void* __restrict__ headW,
                                                   const void* __restrict__ W1,
                                                   const void* __restrict__ W2,
                                                   const int* __restrict__ flag,
                                                   u16* __restrict__ headWT,
                                                   u16* __restrict__ W1T,
                                                   u16* __restrict__ W2T) {
    int isbf = *flag;
    int idx = blockIdx.x * 256 + threadIdx.x;
    if (idx < DD * VV) {                       // 1,024,000
        int k = idx / VV, n = idx - k * VV;
        headWT[n * DD + k] = f2bf(ldf(headW, idx, isbf));
    } else if (idx < DD * VV + EE * DD * FF) { // + 131,072
        int j = idx - DD * VV;
        int e = j >> 14, r = j & 16383, d = r >> 8, f = r & 255;
        W1T[e * 16384 + f * DD + d] = f2bf(ldf(W1, j, isbf));
    } else if (idx < DD * VV + 2 * EE * DD * FF) {
        int j = idx - DD * VV - EE * DD * FF;
        int e = j >> 14, r = j & 16383, f = r >> 6, d = r & 63;
        W2T[e * 16384 + d * FF + f] = f2bf(ldf(W2, j, isbf));
    }
}

// ---------------------------------------------------------------------------
// K1: gather embeddings (-> canonical bf16 emb) + pre[t][b][:] = emb@Wm + bm.
//     4 threads per token (q = quarter of the 64 output columns),
//     float4 LDS reads; summation order per output unchanged.
// ---------------------------------------------------------------------------
__global__ __launch_bounds__(256) void k_embed_pre(const int* __restrict__ x,
                                                   const void* __restrict__ tbl,
                                                   const void* __restrict__ Wm,
                                                   const void* __restrict__ bm,
                                                   const int* __restrict__ flag,
                                                   u16* __restrict__ emb,
                                                   float* __restrict__ pre) {
    __shared__ float sWm[DD * DD];
    __shared__ float sbm[DD];
    int isbf = *flag;
    int tid = threadIdx.x;
    for (int i = tid; i < DD * DD; i += 256) sWm[i] = ldf(Wm, i, isbf);
    if (tid < DD) sbm[tid] = ldf(bm, tid, isbf);
    __syncthreads();

    int gi = blockIdx.x * 256 + tid;           // grid = 128
    int tok = gi >> 2, q = gi & 3;             // 4 threads per token
    int id = x[tok];
    float e[DD];
    if (isbf) {
        const uint4* src = (const uint4*)((const u16*)tbl + id * DD);
        uint4* dst = (uint4*)(emb + tok * DD);
#pragma unroll
        for (int i = 0; i < 8; i++) {
            uint4 v = src[i];
            if ((i >> 1) == q) dst[i] = v;     // each q writes 2 of 8 uint4
            const u16* pu = (const u16*)&v;
#pragma unroll
            for (int j = 0; j < 8; j++) e[i * 8 + j] = bf2f(pu[j]);
        }
    } else {
        const float4* src = (const float4*)((const float*)tbl + id * DD);
        u16* dst = emb + tok * DD;
#pragma unroll
        for (int i = 0; i < 16; i++) {
            float4 v = src[i];
            e[i * 4 + 0] = v.x; e[i * 4 + 1] = v.y;
            e[i * 4 + 2] = v.z; e[i * 4 + 3] = v.w;
            if ((i >> 2) == q) {               // each q writes 4 of 16 pairs
                u32 p0 = (u32)f2bf(v.x) | ((u32)f2bf(v.y) << 16);
                u32 p1 = (u32)f2bf(v.z) | ((u32)f2bf(v.w) << 16);
                ((u32*)dst)[i * 2] = p0;
                ((u32*)dst)[i * 2 + 1] = p1;
            }
        }
    }
    int b = tok >> 10, t = tok & 1023;
    float* prow = pre + (t * BB + b) * DD + q * 16;
#pragma unroll
    for (int j4 = 0; j4 < 4; j4++) {
        int j0 = q * 16 + j4 * 4;
        float a0 = sbm[j0 + 0], a1 = sbm[j0 + 1];
        float a2 = sbm[j0 + 2], a3 = sbm[j0 + 3];
#pragma unroll
        for (int k = 0; k < DD; k++) {
            float ek = e[k];
            float4 wv = *(const float4*)&sWm[k * DD + j0];
            a0 += ek * wv.x; a1 += ek * wv.y;
            a2 += ek * wv.z; a3 += ek * wv.w;
        }
        ((float4*)prow)[j4] = make_float4(a0, a1, a2, a3);
    }
}

// ---------------------------------------------------------------------------
// K2: serial scan. 8 blocks (one per batch row), 1 wave each.
//     lane j owns column j; Um column j in 32 NAMED f32x2 (SSA => VGPRs);
//     mem vector broadcast through LDS (single wave: DS pipe is in-order,
//     compiler inserts the minimal lgkmcnt before the reads' uses).
//     mem_t = tanh(pre_t + mem_{t-1} @ Um), stored f32 [t][b][d].
//     Accumulator pairing identical to R2/R3: Acc0 over k%4 in {0,1},
//     Acc1 over k%4 in {2,3}, hsum ((A0.x+A0.y)+(A1.x+A1.y)).
// ---------------------------------------------------------------------------
__global__ __launch_bounds__(64, 1) void k_scan(const float* __restrict__ pre,
                                                const void* __restrict__ Um,
                                                const int* __restrict__ flag,
                                                float* __restrict__ mem) {
    int isbf = *flag;
    int b = blockIdx.x, j = threadIdx.x;
    __shared__ float sm[DD];

    f32x2 u0, u1, u2, u3, u4, u5, u6, u7, u8, u9, u10, u11, u12, u13, u14, u15,
          u16r, u17, u18, u19, u20, u21, u22, u23, u24, u25, u26, u27, u28, u29,
          u30, u31;
    if (isbf) {
        const u16* up = (const u16*)Um + j;
#define LDU(VAR, I) VAR = (f32x2){bf2f(up[(2 * I) * DD]), bf2f(up[(2 * I + 1) * DD])};
        LDU(u0, 0)  LDU(u1, 1)  LDU(u2, 2)  LDU(u3, 3)
        LDU(u4, 4)  LDU(u5, 5)  LDU(u6, 6)  LDU(u7, 7)
        LDU(u8, 8)  LDU(u9, 9)  LDU(u10, 10) LDU(u11, 11)
        LDU(u12, 12) LDU(u13, 13) LDU(u14, 14) LDU(u15, 15)
        LDU(u16r, 16) LDU(u17, 17) LDU(u18, 18) LDU(u19, 19)
        LDU(u20, 20) LDU(u21, 21) LDU(u22, 22) LDU(u23, 23)
        LDU(u24, 24) LDU(u25, 25) LDU(u26, 26) LDU(u27, 27)
        LDU(u28, 28) LDU(u29, 29) LDU(u30, 30) LDU(u31, 31)
#undef LDU
    } else {
        const float* up = (const float*)Um + j;
#define LDU(VAR, I) VAR = (f32x2){up[(2 * I) * DD], up[(2 * I + 1) * DD]};
        LDU(u0, 0)  LDU(u1, 1)  LDU(u2, 2)  LDU(u3, 3)
        LDU(u4, 4)  LDU(u5, 5)  LDU(u6, 6)  LDU(u7, 7)
        LDU(u8, 8)  LDU(u9, 9)  LDU(u10, 10) LDU(u11, 11)
        LDU(u12, 12) LDU(u13, 13) LDU(u14, 14) LDU(u15, 15)
        LDU(u16r, 16) LDU(u17, 17) LDU(u18, 18) LDU(u19, 19)
        LDU(u20, 20) LDU(u21, 21) LDU(u22, 22) LDU(u23, 23)
        LDU(u24, 24) LDU(u25, 25) LDU(u26, 26) LDU(u27, 27)
        LDU(u28, 28) LDU(u29, 29) LDU(u30, 30) LDU(u31, 31)
#undef LDU
    }
    sm[j] = 0.f;

    float pcur = pre[b * DD + j];   // t = 0
    for (int t = 0; t < TT; t++) {
        int tn = (t + 1 < TT) ? t + 1 : t;
        float pnext = pre[(tn * BB + b) * DD + j];   // prefetch (vmcnt only)
        const f32x4* m4 = (const f32x4*)sm;
        f32x2 A0 = {0.f, 0.f}, A1 = {0.f, 0.f};
#define STEP(K, UL, UH) { f32x4 m = m4[K];                      \
        A0 += __builtin_shufflevector(m, m, 0, 1) * UL;         \
        A1 += __builtin_shufflevector(m, m, 2, 3) * UH; }
        STEP(0, u0, u1)   STEP(1, u2, u3)   STEP(2, u4, u5)   STEP(3, u6, u7)
        STEP(4, u8, u9)   STEP(5, u10, u11) STEP(6, u12, u13) STEP(7, u14, u15)
        STEP(8, u16r, u17) STEP(9, u18, u19) STEP(10, u20, u21) STEP(11, u22, u23)
        STEP(12, u24, u25) STEP(13, u26, u27) STEP(14, u28, u29) STEP(15, u30, u31)
#undef STEP
        float s = ((A0.x + A0.y) + (A1.x + A1.y)) + pcur;
        // tanh(s) = 1 - 2/(e^{2s}+1); exp->inf / ->0 both give correct +/-1
        float ex = __expf(2.f * s);
        float mn = 1.f - 2.f * __builtin_amdgcn_rcpf(ex + 1.f);
        mem[(t * BB + b) * DD + j] = mn;
        sm[j] = mn;     // single wave: DS in-order; next iter's reads see it
        pcur = pnext;
    }
}

// ---------------------------------------------------------------------------
// K3: expert FFN. block = (expert e, 64 tokens); wave w = 16 tokens.
//     GEMM1: h = gelu(emb @ W1_e + b1_e); LDS round-trip (C->A layout);
//     GEMM2: eo = h @ W2_e + b2_e -> bf16 eo[tok][e][d].
// ---------------------------------------------------------------------------
__global__ __launch_bounds__(256) void k_ffn(const u16* __restrict__ emb,
                                             const u16* __restrict__ W1T,
                                             const void* __restrict__ b1g,
                                             const u16* __restrict__ W2T,
                                             const void* __restrict__ b2g,
                                             const int* __restrict__ flag,
                                             u16* __restrict__ eo) {
    __shared__ u16 hh[4][16 * 264];          // 264 = 256 + 8 pad
    int isbf = *flag;
    int e = blockIdx.x, mb = blockIdx.y;
    int w = threadIdx.x >> 6, l = threadIdx.x & 63;
    int lr = l & 15, lq = l >> 4;
    int m0 = mb * 64 + w * 16;

    short8 a0 = ld8(emb + (m0 + lr) * DD + lq * 8);
    short8 a1 = ld8(emb + (m0 + lr) * DD + 32 + lq * 8);
    const u16* w1 = W1T + e * 16384;

    f32x4 acc[16];
#pragma unroll
    for (int nt = 0; nt < 16; nt++) {
        int n = nt * 16 + lr;
        short8 bf0 = ld8(w1 + n * DD + lq * 8);
        short8 bf1 = ld8(w1 + n * DD + 32 + lq * 8);
        f32x4 c = {0.f, 0.f, 0.f, 0.f};
        c = __builtin_amdgcn_mfma_f32_16x16x32_bf16(a0, bf0, c, 0, 0, 0);
        c = __builtin_amdgcn_mfma_f32_16x16x32_bf16(a1, bf1, c, 0, 0, 0);
        acc[nt] = c;
    }
    u16* hw = hh[w];
#pragma unroll
    for (int nt = 0; nt < 16; nt++) {
        int n = nt * 16 + lr;
        float bb = ldf(b1g, e * FF + n, isbf);
#pragma unroll
        for (int r = 0; r < 4; r++) {
            float xv = acc[nt][r] + bb;
            float g = 0.5f * xv * (1.f + erff(xv * 0.70710678118654752f));
            hw[(lq * 4 + r) * 264 + n] = f2bf(g);
        }
    }
    __syncthreads();

    f32x4 acc2[4];
#pragma unroll
    for (int dt = 0; dt < 4; dt++) acc2[dt] = (f32x4){0.f, 0.f, 0.f, 0.f};
    const u16* w2 = W2T + e * 16384;
#pragma unroll
    for (int kb = 0; kb < 8; kb++) {
        short8 af = ld8(hw + lr * 264 + kb * 32 + lq * 8);
#pragma unroll
        for (int dt = 0; dt < 4; dt++) {
            short8 bf = ld8(w2 + (dt * 16 + lr) * FF + kb * 32 + lq * 8);
            acc2[dt] = __builtin_amdgcn_mfma_f32_16x16x32_bf16(af, bf, acc2[dt], 0, 0, 0);
        }
    }
#pragma unroll
    for (int dt = 0; dt < 4; dt++) {
        int d = dt * 16 + lr;
        float bb = ldf(b2g, e * DD + d, isbf);
#pragma unroll
        for (int r = 0; r < 4; r++) {
            int tok = m0 + lq * 4 + r;
            eo[(tok * EE + e) * DD + d] = f2bf(acc2[dt][r] + bb);
        }
    }
}

// ---------------------------------------------------------------------------
// K4: gates[tok][:] = softmax(mem[t][b][:] @ Wg + bg).  thread = token.
// ---------------------------------------------------------------------------
__global__ __launch_bounds__(256) void k_gates(const float* __restrict__ mem,
                                               const void* __restrict__ Wg,
                                               const void* __restrict__ bg,
                                               const int* __restrict__ flag,
                                               float* __restrict__ gates) {
    __shared__ float sWg[DD * EE];
    int isbf = *flag;
    int tid = threadIdx.x;
    for (int i = tid; i < DD * EE; i += 256) sWg[i] = ldf(Wg, i, isbf);
    __syncthreads();

    int tok = blockIdx.x * 256 + tid;
    int b = tok >> 10, t = tok & 1023;
    const float* mr = mem + (t * BB + b) * DD;
    float z[EE];
#pragma unroll
    for (int e = 0; e < EE; e++) z[e] = ldf(bg, e, isbf);
    const float4* wg4 = (const float4*)sWg;
    const float4* mr4 = (const float4*)mr;
    for (int k4 = 0; k4 < 16; k4++) {
        float4 mv = mr4[k4];
        float m[4] = {mv.x, mv.y, mv.z, mv.w};
#pragma unroll
        for (int kk = 0; kk < 4; kk++) {
            int k = k4 * 4 + kk;
            float4 wa = wg4[k * 2], wb = wg4[k * 2 + 1];
            z[0] += m[kk] * wa.x; z[1] += m[kk] * wa.y;
            z[2] += m[kk] * wa.z; z[3] += m[kk] * wa.w;
            z[4] += m[kk] * wb.x; z[5] += m[kk] * wb.y;
            z[6] += m[kk] * wb.z; z[7] += m[kk] * wb.w;
        }
    }
    float zm = z[0];
#pragma unroll
    for (int e = 1; e < EE; e++) zm = fmaxf(zm, z[e]);
    float sum = 0.f;
#pragma unroll
    for (int e = 0; e < EE; e++) { z[e] = __expf(z[e] - zm); sum += z[e]; }
    float rs = __builtin_amdgcn_rcpf(sum);
#pragma unroll
    for (int e = 0; e < EE; e++) gates[tok * EE + e] = z[e] * rs;
}

// ---------------------------------------------------------------------------
// K5: out = LayerNorm(emb + sum_e gates_e * eo_e) -> canonical bf16 outb.
// ---------------------------------------------------------------------------
__global__ __launch_bounds__(256) void k_ln(const u16* __restrict__ emb,
                                            const u16* __restrict__ eo,
                                            const float* __restrict__ gates,
                                            const void* __restrict__ ln_g,
                                            const void* __restrict__ ln_b,
                                            const int* __restrict__ flag,
                                            u16* __restrict__ outb) {
    int isbf = *flag;
    int w = threadIdx.x >> 6, l = threadIdx.x & 63;
    int tok = blockIdx.x * 4 + w;
    const float* g = gates + tok * EE;
    const u16* er = eo + tok * EE * DD;
    float moe = 0.f;
#pragma unroll
    for (int e = 0; e < EE; e++) moe += g[e] * bf2f(er[e * DD + l]);
    float y = bf2f(emb[tok * DD + l]) + moe;
    float s = y;
#pragma unroll
    for (int off = 32; off > 0; off >>= 1) s += __shfl_xor(s, off, 64);
    float mu = s * (1.f / 64.f);
    float d = y - mu;
    float s2 = d * d;
#pragma unroll
    for (int off = 32; off > 0; off >>= 1) s2 += __shfl_xor(s2, off, 64);
    float var = s2 * (1.f / 64.f);
    float r = rsqrtf(var + 1e-5f);
    float o = ldf(ln_g, l, isbf) * d * r + ldf(ln_b, l, isbf);
    outb[tok * DD + l] = f2bf(o);
}

// ---------------------------------------------------------------------------
// K6: head GEMM. logits = out @ head_W + head_b  [8192 x 16000].
//     Output dtype per flag (bf16 or f32).
// ---------------------------------------------------------------------------
__global__ __launch_bounds__(256) void k_head(const u16* __restrict__ outb,
                                              const u16* __restrict__ headWT,
                                              const void* __restrict__ head_b,
                                              const int* __restrict__ flag,
                                              void* __restrict__ logits) {
    int isbf = *flag;
    int nb = blockIdx.x, mb = blockIdx.y;
    int w = threadIdx.x >> 6, l = threadIdx.x & 63;
    int lr = l & 15, lq = l >> 4;
    int m0 = mb * 64 + w * 16;
    int n0 = nb * 256;
    int ntc = (nb == 62) ? 8 : 16;

    short8 a0 = ld8(outb + (m0 + lr) * DD + lq * 8);
    short8 a1 = ld8(outb + (m0 + lr) * DD + 32 + lq * 8);

    for (int nt = 0; nt < ntc; nt++) {
        int n = n0 + nt * 16 + lr;
        short8 bf0 = ld8(headWT + n * DD + lq * 8);
        short8 bf1 = ld8(headWT + n * DD + 32 + lq * 8);
        f32x4 c = {0.f, 0.f, 0.f, 0.f};
        c = __builtin_amdgcn_mfma_f32_16x16x32_bf16(a0, bf0, c, 0, 0, 0);
        c = __builtin_amdgcn_mfma_f32_16x16x32_bf16(a1, bf1, c, 0, 0, 0);
        float hb = ldf(head_b, n, isbf);
        if (isbf) {
#pragma unroll
            for (int r = 0; r < 4; r++)
                ((u16*)logits)[(m0 + lq * 4 + r) * VV + n] = f2bf(c[r] + hb);
        } else {
#pragma unroll
            for (int r = 0; r < 4; r++)
                ((float*)logits)[(m0 + lq * 4 + r) * VV + n] = c[r] + hb;
        }
    }
}

// ---------------------------------------------------------------------------
extern "C" void kernel_launch(void* const* d_in, const int* in_sizes, int n_in,
                              void* d_out, int out_size, void* d_ws, size_t ws_size,
                              hipStream_t stream) {
    const int*  x      = (const int*)d_in[0];
    const void* tbl    = d_in[1];
    const void* Wm     = d_in[2];
    const void* Um     = d_in[3];
    const void* bm     = d_in[4];
    const void* Wg     = d_in[5];
    const void* bg     = d_in[6];
    const void* W1     = d_in[7];
    const void* b1     = d_in[8];
    const void* W2     = d_in[9];
    const void* b2     = d_in[10];
    const void* ln_g   = d_in[11];
    const void* ln_b   = d_in[12];
    const void* headW  = d_in[13];
    const void* head_b = d_in[14];

    char* w = (char*)d_ws;
    int*   flag   = (int*)(w);                    // 256 B
    u16*   headWT = (u16*)(w + 0x0000100);        // 2,048,000 B
    u16*   W1T    = (u16*)(w + 0x0200000);        //   262,144 B
    u16*   W2T    = (u16*)(w + 0x0240000);        //   262,144 B
    u16*   emb    = (u16*)(w + 0x0280000);        // 1,048,576 B
    u16*   outb   = (u16*)(w + 0x0380000);        // 1,048,576 B
    float* pre    = (float*)(w + 0x0480000);      // 2,097,152 B
    float* mem    = (float*)(w + 0x0680000);      // 2,097,152 B
    float* gates  = (float*)(w + 0x0880000);      //   262,144 B
    u16*   eo     = (u16*)(w + 0x08C0000);        // 8,388,608 B  (end 17.6 MB)

    k_sniff<<<dim3(1), dim3(256), 0, stream>>>((const u32*)tbl, flag);
    k_transpose<<<dim3((DD * VV + 2 * EE * DD * FF + 255) / 256), dim3(256), 0, stream>>>(
        headW, W1, W2, flag, headWT, W1T, W2T);
    k_embed_pre<<<dim3(BT * 4 / 256), dim3(256), 0, stream>>>(x, tbl, Wm, bm, flag, emb, pre);
    k_scan<<<dim3(BB), dim3(64), 0, stream>>>(pre, Um, flag, mem);
    k_ffn<<<dim3(EE, BT / 64), dim3(256), 0, stream>>>(emb, W1T, b1, W2T, b2, flag, eo);
    k_gates<<<dim3(BT / 256), dim3(256), 0, stream>>>(mem, Wg, bg, flag, gates);
    k_ln<<<dim3(BT / 4), dim3(256), 0, stream>>>(emb, eo, gates, ln_g, ln_b, flag, outb);
    k_head<<<dim3(63, BT / 64), dim3(256), 0, stream>>>(outb, headWT, head_b, flag, d_out);
}